// Round 9
// baseline (259.289 us; speedup 1.0000x reference)
//
#include <hip/hip_runtime.h>
#include <cmath>

#define B_    4
#define S_    1024
#define DIN_  256
#define M_    1024
#define H_    16
#define F_    8
#define L_    2
#define DOUT_ 256
#define NT_   4096   // B*S tokens

typedef unsigned short u16;
typedef unsigned int   u32;
typedef __bf16 bf16x8 __attribute__((ext_vector_type(8)));
typedef __bf16 bf16x4v __attribute__((ext_vector_type(4)));
typedef float  f32x4  __attribute__((ext_vector_type(4)));

#define LOG2E 1.4426950408889634f
#define QSCALE (0.125f * LOG2E)

__device__ __forceinline__ u16 f2b(float f) {
    u32 u = __builtin_bit_cast(u32, f);
    u += 0x7fffu + ((u >> 16) & 1u);
    return (u16)(u >> 16);
}
__device__ __forceinline__ float b2f(u32 h) {
    return __builtin_bit_cast(float, h << 16);
}
// async global->LDS, 16B per lane; LDS dest must be wave-uniform base (+lane*16 by HW)
__device__ __forceinline__ void gload_lds16(const void* g, void* l) {
    __builtin_amdgcn_global_load_lds(
        (const __attribute__((address_space(1))) u32*)g,
        (__attribute__((address_space(3))) u32*)l, 16, 0, 0);
}

// ---------------------------------------------------------------------------
// Unified prep kernel. Trig restructured: ONE sincosf per (s,f) pair,
// broadcast-multiplied over the 32 (l,h) pbias rows (540K trig -> 8K).
// Block-id ranges:
//   [0,1024) x->bf16 | [1024,7168) WqkvT | [7168,9216) WoT | [9216,9472) WembT
//   [9472,9984) W1T | [9984,10112) W2T | [10112,10144) csb+qcs | [10144,10168) bqkv
// ---------------------------------------------------------------------------
__device__ __forceinline__ void tileT(float (*t)[33], const float* src,
                                      u16* dst, int K, int N, int n0, int k0,
                                      int tid)
{
    const int r = tid >> 3, c4 = (tid & 7) << 2;
    float4 v = *(const float4*)(src + (size_t)(k0 + r) * N + n0 + c4);
    t[r][c4 + 0] = v.x; t[r][c4 + 1] = v.y; t[r][c4 + 2] = v.z; t[r][c4 + 3] = v.w;
    __syncthreads();
    ushort4 o = make_ushort4(f2b(t[c4 + 0][r]), f2b(t[c4 + 1][r]),
                             f2b(t[c4 + 2][r]), f2b(t[c4 + 3][r]));
    *(ushort4*)(dst + (size_t)(n0 + r) * K + k0 + c4) = o;
}

__global__ __launch_bounds__(256) void prep_k(
    const float* __restrict__ x, const float* __restrict__ Wemb,
    const float* __restrict__ Wq, const float* __restrict__ Wk,
    const float* __restrict__ Wv, const float* __restrict__ Wo,
    const float* __restrict__ W1, const float* __restrict__ W2,
    const float* __restrict__ freqs, const float* __restrict__ poff,
    const float* __restrict__ pb, const float* __restrict__ bq,
    const float* __restrict__ bk, const float* __restrict__ bv,
    u16* __restrict__ xb, u16* __restrict__ WembT, u16* __restrict__ WqkvT,
    u16* __restrict__ WoT, u16* __restrict__ W1T, u16* __restrict__ W2T,
    u16* __restrict__ qcs, u16* __restrict__ csb, float* __restrict__ bqkv)
{
    __shared__ float t[32][33];
    const int bid = blockIdx.x, tid = threadIdx.x;

    if (bid < 1024) {                       // x -> bf16
        int i = (bid * 256 + tid) * 4;
        float4 v = *(const float4*)(x + i);
        *(ushort4*)(xb + i) = make_ushort4(f2b(v.x), f2b(v.y), f2b(v.z), f2b(v.w));
    } else if (bid < 7168) {                // WqkvT
        int id = bid - 1024;
        int z = id >> 10, rem = id & 1023;
        int n0 = (rem & 31) << 5, k0 = (rem >> 5) << 5;
        int l = z / 3, which = z - l * 3;
        const float* src = (which == 0 ? Wq : which == 1 ? Wk : Wv) + (size_t)l * M_ * M_;
        u16* d = WqkvT + (size_t)l * 3072 * 1024 + (size_t)which * 1024 * 1024;
        tileT(t, src, d, 1024, 1024, n0, k0, tid);
    } else if (bid < 9216) {                // WoT
        int id = bid - 7168;
        int z = id >> 10, rem = id & 1023;
        int n0 = (rem & 31) << 5, k0 = (rem >> 5) << 5;
        tileT(t, Wo + (size_t)z * M_ * M_, WoT + (size_t)z * M_ * M_,
              1024, 1024, n0, k0, tid);
    } else if (bid < 9472) {                // WembT (K=256, N=1024)
        int id = bid - 9216;
        int n0 = (id & 31) << 5, k0 = (id >> 5) << 5;
        tileT(t, Wemb, WembT, 256, 1024, n0, k0, tid);
    } else if (bid < 9984) {                // W1T (K=1024, N=512)
        int id = bid - 9472;
        int n0 = (id & 15) << 5, k0 = (id >> 4) << 5;
        tileT(t, W1, W1T, 1024, 512, n0, k0, tid);
    } else if (bid < 10112) {               // W2T (K=512, N=256)
        int id = bid - 9984;
        int n0 = (id & 7) << 5, k0 = (id >> 3) << 5;
        tileT(t, W2, W2T, 512, 256, n0, k0, tid);
    } else if (bid < 10144) {               // csb + qcs tables (1 sincos/(s,f))
        int idx = (bid - 10112) * 256 + tid;   // 0..8191 = s*8 + f
        int s = idx >> 3, f = idx & 7;
        float pc = ((float)s * (6.283185307179586f / 1024.f)) * freqs[f] + poff[f];
        float sn, cs;
        __sincosf(pc, &sn, &cs);
        csb[s * 16 + f] = f2b(cs);
        csb[s * 16 + f + 8] = f2b(sn);
#pragma unroll
        for (int lh = 0; lh < 32; ++lh) {
            float p = pb[lh * 8 + f] * LOG2E;
            qcs[lh * 16384 + s * 16 + f] = f2b(p * cs);
            qcs[lh * 16384 + s * 16 + f + 8] = f2b(p * sn);
        }
    } else {                                // bias concat
        int idx = (bid - 10144) * 256 + tid;   // 0..6143
        int l = idx >= 3072;
        int j = idx - l * 3072;
        float v = (j < 1024) ? bq[l * 1024 + j]
                : (j < 2048) ? bk[l * 1024 + j - 1024]
                             : bv[l * 1024 + j - 2048];
        bqkv[idx] = v;
    }
}

// ---------------------------------------------------------------------------
// 256x256-tile QKV GEMM, BK=32, 3-slot LDS ring, counted-vmcnt deep pipeline.
// 512 thr = 8 waves (2 wr x 4 wc); per-wave C = 128x64 (8 mf x 4 nf frags).
// Iter t: stage K-tile t+2 into slot (t+2)%3, vmcnt(8) retires tile t's 4
// loads/thread (t+1,t+2 stay in flight = 2-iteration latency slack), barrier,
// 12 ds_read_b128 + 32 MFMA, barrier. Swizzle kg = g ^ ((row>>2)&3): exact
// 2-way banks (free). Epilogue: Q cols *QSCALE, K plain, V -> Vtg transposed.
// ---------------------------------------------------------------------------
__global__ __launch_bounds__(512, 2) void qkv256_k(
    const u16* __restrict__ A, const u16* __restrict__ Wt,
    const float* __restrict__ bias, u16* __restrict__ Cout,
    u16* __restrict__ vt)
{
    __shared__ __attribute__((aligned(16))) u16 As[3 * 256 * 32];
    __shared__ __attribute__((aligned(16))) u16 Bs[3 * 256 * 32];
    const int tid = threadIdx.x, lane = tid & 63;
    const int wid = tid >> 6, wr = wid >> 2, wc = wid & 3;
    const int r = lane & 15, g = lane >> 4;
    const int bn = blockIdx.x % 12, bm = blockIdx.x / 12;
    const int K = 1024;

    f32x4 acc[8][4];
#pragma unroll
    for (int mf = 0; mf < 8; ++mf)
#pragma unroll
        for (int nf = 0; nf < 4; ++nf) {
            f32x4 z = {0.f, 0.f, 0.f, 0.f};
            acc[mf][nf] = z;
        }

    // stage K-tile kt into ring slot: 2 A-loads + 2 B-loads per thread
    auto STAGE = [&](int slot, int kt) {
        u16* As0 = As + slot * (256 * 32);
        u16* Bs0 = Bs + slot * (256 * 32);
#pragma unroll
        for (int i = 0; i < 2; ++i) {
            int s = i * 512 + tid;
            int row = s >> 2, gi = s & 3;
            int kg = gi ^ ((row >> 2) & 3);
            gload_lds16(A + (size_t)(bm * 256 + row) * K + kt * 32 + kg * 8,
                        As0 + (size_t)(s & ~63) * 8);
            gload_lds16(Wt + (size_t)(bn * 256 + row) * K + kt * 32 + kg * 8,
                        Bs0 + (size_t)(s & ~63) * 8);
        }
    };

    STAGE(0, 0);
    STAGE(1, 1);
    __builtin_amdgcn_sched_barrier(0);

    int slot = 0;
    for (int t = 0; t < 32; ++t) {
        if (t < 30) {
            int nb = slot + 2; if (nb >= 3) nb -= 3;
            STAGE(nb, t + 2);
            asm volatile("s_waitcnt vmcnt(8)" ::: "memory");   // tile t done
        } else if (t == 30) {
            asm volatile("s_waitcnt vmcnt(4)" ::: "memory");
        } else {
            asm volatile("s_waitcnt vmcnt(0)" ::: "memory");
        }
        __builtin_amdgcn_sched_barrier(0);
        __builtin_amdgcn_s_barrier();       // all waves' tile-t writes visible
        __builtin_amdgcn_sched_barrier(0);

        const u16* As0 = As + slot * (256 * 32);
        const u16* Bs0 = Bs + slot * (256 * 32);
        bf16x8 af[8], bfr[4];
        const int kg = (g ^ ((r >> 2) & 3)) * 8;   // lane's swizzled k-granule
#pragma unroll
        for (int mf = 0; mf < 8; ++mf)
            af[mf] = *(const bf16x8*)(As0 + (wr * 128 + mf * 16 + r) * 32 + kg);
#pragma unroll
        for (int nf = 0; nf < 4; ++nf)
            bfr[nf] = *(const bf16x8*)(Bs0 + (wc * 64 + nf * 16 + r) * 32 + kg);

        __builtin_amdgcn_s_setprio(1);
#pragma unroll
        for (int mf = 0; mf < 8; ++mf)
#pragma unroll
            for (int nf = 0; nf < 4; ++nf)
                acc[mf][nf] = __builtin_amdgcn_mfma_f32_16x16x32_bf16(
                    af[mf], bfr[nf], acc[mf][nf], 0, 0, 0);
        __builtin_amdgcn_s_setprio(0);

        __builtin_amdgcn_sched_barrier(0);
        __builtin_amdgcn_s_barrier();       // all waves done reading slot
        __builtin_amdgcn_sched_barrier(0);
        slot = (slot == 2) ? 0 : slot + 1;
    }

    // epilogue: row = bm*256 + wr*128 + mf*16 + g*4 + q ; col = bn*256+wc*64+nf*16+r
#pragma unroll
    for (int nf = 0; nf < 4; ++nf) {
        const int gcol = bn * 256 + wc * 64 + nf * 16 + r;
        const float bb = bias[gcol];
#pragma unroll
        for (int mf = 0; mf < 8; ++mf) {
            const int grow0 = bm * 256 + wr * 128 + mf * 16 + g * 4;
            if (gcol >= 2048) {
                // V^T: vt[(bh*64 + d%64)*1024 + token], 4 consecutive tokens
                int d = gcol - 2048;
                int bh = (grow0 >> 10) * 16 + (d >> 6);
                u16 pk[4];
#pragma unroll
                for (int q = 0; q < 4; ++q) pk[q] = f2b(acc[mf][nf][q] + bb);
                uint2 pv;
                pv.x = (u32)pk[0] | ((u32)pk[1] << 16);
                pv.y = (u32)pk[2] | ((u32)pk[3] << 16);
                *(uint2*)(vt + ((size_t)bh * 64 + (d & 63)) * 1024 + (grow0 & 1023)) = pv;
            } else {
                const float sc = (gcol < 1024) ? QSCALE : 1.f;
#pragma unroll
                for (int q = 0; q < 4; ++q) {
                    float c = (acc[mf][nf][q] + bb) * sc;
                    Cout[(size_t)(grow0 + q) * 3072 + gcol] = f2b(c);
                }
            }
        }
    }
}

// ---------------------------------------------------------------------------
// bf16 MFMA GEMM (128/64-row tiles) for emb/Wo/MLP.
// EPI: 0 none, 1 |c|*0.125, 2 relu, 6 +residual from vt (bf16).
// ---------------------------------------------------------------------------
template<int EPI, int OUTBF, int BM>
__global__ __launch_bounds__(256, 2) void mgemm_k(
    const u16* __restrict__ A, const u16* __restrict__ Wt,
    const float* __restrict__ bias, void* __restrict__ Cout,
    u16* __restrict__ vt, int N, int K)
{
    constexpr int MR = BM / 32;             // m-frags per wave
    __shared__ __attribute__((aligned(16))) u16 As[BM * 64];
    __shared__ __attribute__((aligned(16))) u16 Bs[128 * 64];
    const int tid = threadIdx.x;
    const int lane = tid & 63;
    const int bn = blockIdx.x, bm = blockIdx.y;
    const int wid = tid >> 6, wr = wid >> 1, wc = wid & 1;

    f32x4 acc[MR][4];
#pragma unroll
    for (int m = 0; m < MR; ++m)
#pragma unroll
        for (int n = 0; n < 4; ++n) {
            f32x4 z = {0.f, 0.f, 0.f, 0.f};
            acc[m][n] = z;
        }

    const int r = lane & 15, g = lane >> 4;
    const int nk = K >> 6;

    for (int kt = 0; kt < nk; ++kt) {
        const int k0 = kt << 6;
        __syncthreads();
#pragma unroll
        for (int i = 0; i < (BM >> 5); ++i) {
            int slot = i * 256 + tid;
            int row = slot >> 3;
            int kg = (slot & 7) ^ (row & 7);
            gload_lds16(A + (size_t)(bm * BM + row) * K + k0 + kg * 8,
                        As + (size_t)(slot & ~63) * 8);
        }
#pragma unroll
        for (int i = 0; i < 4; ++i) {
            int slot = i * 256 + tid;
            int row = slot >> 3;
            int kg = (slot & 7) ^ (row & 7);
            gload_lds16(Wt + (size_t)(bn * 128 + row) * K + k0 + kg * 8,
                        Bs + (size_t)(slot & ~63) * 8);
        }
        __syncthreads();

#pragma unroll
        for (int ks = 0; ks < 2; ++ks) {
            bf16x8 af[MR], bfr[4];
#pragma unroll
            for (int m = 0; m < MR; ++m) {
                int row = wr * (BM >> 1) + m * 16 + r;
                int kg = (ks * 4 + g) ^ (row & 7);
                af[m] = *(const bf16x8*)(As + row * 64 + kg * 8);
            }
#pragma unroll
            for (int n = 0; n < 4; ++n) {
                int row = wc * 64 + n * 16 + r;
                int kg = (ks * 4 + g) ^ (row & 7);
                bfr[n] = *(const bf16x8*)(Bs + row * 64 + kg * 8);
            }
#pragma unroll
            for (int m = 0; m < MR; ++m)
#pragma unroll
                for (int n = 0; n < 4; ++n)
                    acc[m][n] = __builtin_amdgcn_mfma_f32_16x16x32_bf16(
                        af[m], bfr[n], acc[m][n], 0, 0, 0);
        }
    }

#pragma unroll
    for (int n = 0; n < 4; ++n) {
        const int gcol = bn * 128 + wc * 64 + n * 16 + r;
        const float bb = bias[gcol];
#pragma unroll
        for (int m = 0; m < MR; ++m) {
            const int grow0 = bm * BM + wr * (BM >> 1) + m * 16 + g * 4;
#pragma unroll
            for (int q = 0; q < 4; ++q) {
                float c = acc[m][n][q] + bb;
                if (EPI == 1) c = fabsf(c) * 0.125f;
                if (EPI == 2) c = fmaxf(c, 0.f);
                if (EPI == 6)
                    c += b2f(vt[(size_t)(grow0 + q) * N + gcol]);  // residual
                if (OUTBF)
                    ((u16*)Cout)[(size_t)(grow0 + q) * N + gcol] = f2b(c);
                else
                    ((float*)Cout)[(size_t)(grow0 + q) * N + gcol] = c;
            }
        }
    }
}

// ---------------------------------------------------------------------------
// MFMA flash attention (unchanged from r7/r8): 3-deep prefetch, counted vmcnt,
// XCD-colocated grid, no-max exp2 softmax, swapped QK^T, 4 waves x 32q.
// ---------------------------------------------------------------------------
__global__ __launch_bounds__(256) void fattn_k(
    const u16* __restrict__ QKV, const u16* __restrict__ Vtg,
    const u16* __restrict__ csb, const u16* __restrict__ qcs,
    u16* __restrict__ Og)
{
    __shared__ __attribute__((aligned(16))) u16 Ks3[3][64 * 64];
    __shared__ __attribute__((aligned(16))) u16 Vt3[3][64 * 64];
    __shared__ __attribute__((aligned(16))) u16 Ext[3][64 * 16];
    __shared__ __attribute__((aligned(16))) u16 Pl[4][32 * 68];
    const int tid = threadIdx.x, lane = tid & 63, w = tid >> 6;
    const int c = lane & 15, g = lane >> 4;
    const int Lid = blockIdx.x;
    const int slot = Lid >> 3;
    const int grp = (Lid & 7) * 8 + (slot >> 3);      // (b*16+h)
    const int qi = slot & 7;
    const int b = grp >> 4, h = grp & 15, bh = grp;
    const int s0 = qi * 128;

    const uint4 zz = {0u, 0u, 0u, 0u};
    const bf16x8 zfrag = __builtin_bit_cast(bf16x8, zz);

    bf16x8 aq[2][3];
#pragma unroll
    for (int m = 0; m < 2; ++m) {
        int sl = s0 + w * 32 + m * 16 + c;
        size_t tok = (size_t)b * 1024 + sl;
        aq[m][0] = *(const bf16x8*)(QKV + tok * 3072 + h * 64 + g * 8);
        aq[m][1] = *(const bf16x8*)(QKV + tok * 3072 + h * 64 + 32 + g * 8);
        aq[m][2] = (g < 2) ? *(const bf16x8*)(qcs + ((size_t)h * 1024 + sl) * 16 + g * 8)
                           : zfrag;
    }
    __builtin_amdgcn_sched_barrier(0);

    f32x4 oacc[2][4];
#pragma unroll
    for (int m = 0; m < 2; ++m)
#pragma unroll
        for (int n = 0; n < 4; ++n) {
            f32x4 z = {0.f, 0.f, 0.f, 0.f};
            oacc[m][n] = z;
        }
    float lsum[2] = {0.f, 0.f};

    auto STAGE = [&](int buf, int t0) {
#pragma unroll
        for (int i = 0; i < 2; ++i) {
            int sl2 = i * 256 + tid;
            int row = sl2 >> 3, gi = sl2 & 7;
            int kg = (gi ^ (row & 7)) * 8;
            gload_lds16(QKV + (size_t)(b * 1024 + t0 + row) * 3072 + 1024 + h * 64 + kg,
                        &Ks3[buf][(size_t)(sl2 & ~63) * 8]);
            gload_lds16(Vtg + (size_t)(bh * 64 + row) * 1024 + t0 + kg,
                        &Vt3[buf][(size_t)(sl2 & ~63) * 8]);
        }
        if (tid < 128) {
            int r2 = tid >> 1, g2 = tid & 1;
            gload_lds16(csb + (size_t)(t0 + r2) * 16 + g2 * 8,
                        &Ext[buf][(size_t)(tid & ~63) * 8]);
        }
    };

    STAGE(0, 0);
    STAGE(1, 64);
    __builtin_amdgcn_sched_barrier(0);

    int cur = 0;
    for (int it = 0; it < 16; ++it) {
        if (it < 14) {
            int nb = cur + 2; if (nb >= 3) nb -= 3;
            STAGE(nb, (it + 2) << 6);
            if (w < 2) asm volatile("s_waitcnt vmcnt(10)" ::: "memory");
            else       asm volatile("s_waitcnt vmcnt(8)" ::: "memory");
        } else if (it == 14) {
            if (w < 2) asm volatile("s_waitcnt vmcnt(5)" ::: "memory");
            else       asm volatile("s_waitcnt vmcnt(4)" ::: "memory");
        } else {
            asm volatile("s_waitcnt vmcnt(0)" ::: "memory");
        }
        __builtin_amdgcn_sched_barrier(0);
        __builtin_amdgcn_s_barrier();
        __builtin_amdgcn_sched_barrier(0);

        const u16* ksb = &Ks3[cur][0];
        const u16* vtb = &Vt3[cur][0];
        const u16* exb = &Ext[cur][0];

        f32x4 sacc[2][4];
#pragma unroll
        for (int m = 0; m < 2; ++m)
#pragma unroll
            for (int n = 0; n < 4; ++n) {
                f32x4 z = {0.f, 0.f, 0.f, 0.f};
                sacc[m][n] = z;
            }
        __builtin_amdgcn_s_setprio(1);
#pragma unroll
        for (int ks = 0; ks < 3; ++ks) {
            bf16x8 bk[4];
#pragma unroll
            for (int n = 0; n < 4; ++n) {
                int tr = n * 16 + c;
                if (ks < 2) {
                    int kg = (ks * 4 + g) ^ (tr & 7);
                    bk[n] = *(const bf16x8*)(ksb + tr * 64 + kg * 8);
                } else {
                    bk[n] = (g < 2) ? *(const bf16x8*)(exb + tr * 16 + g * 8) : zfrag;
                }
            }
#pragma unroll
            for (int n = 0; n < 4; ++n)
#pragma unroll
                for (int m = 0; m < 2; ++m)
                    sacc[m][n] = __builtin_amdgcn_mfma_f32_16x16x32_bf16(
                        bk[n], aq[m][ks], sacc[m][n], 0, 0, 0);
        }
        __builtin_amdgcn_s_setprio(0);

#pragma unroll
        for (int m = 0; m < 2; ++m)
#pragma unroll
            for (int n = 0; n < 4; ++n) {
                float p0 = __builtin_amdgcn_exp2f(sacc[m][n][0]);
                float p1 = __builtin_amdgcn_exp2f(sacc[m][n][1]);
                float p2 = __builtin_amdgcn_exp2f(sacc[m][n][2]);
                float p3 = __builtin_amdgcn_exp2f(sacc[m][n][3]);
                lsum[m] += (p0 + p1) + (p2 + p3);
                bf16x4v pk;
                pk[0] = (__bf16)p0; pk[1] = (__bf16)p1;
                pk[2] = (__bf16)p2; pk[3] = (__bf16)p3;
                *(bf16x4v*)(&Pl[w][(m * 16 + c) * 68 + n * 16 + g * 4]) = pk;
            }

        __builtin_amdgcn_s_setprio(1);
#pragma unroll
        for (int ks2 = 0; ks2 < 2; ++ks2) {
            bf16x8 pa[2];
#pragma unroll
            for (int m = 0; m < 2; ++m)
                pa[m] = *(const bf16x8*)(&Pl[w][(m * 16 + c) * 68 + ks2 * 32 + g * 8]);
#pragma unroll
            for (int n = 0; n < 4; ++n) {
                int dr = n * 16 + c;
                int kg = (ks2 * 4 + g) ^ (dr & 7);
                bf16x8 vf = *(const bf16x8*)(vtb + dr * 64 + kg * 8);
#pragma unroll
                for (int m = 0; m < 2; ++m)
                    oacc[m][n] = __builtin_amdgcn_mfma_f32_16x16x32_bf16(
                        pa[m], vf, oacc[m][n], 0, 0, 0);
            }
        }
        __builtin_amdgcn_s_setprio(0);

        __builtin_amdgcn_sched_barrier(0);
        __builtin_amdgcn_s_barrier();
        __builtin_amdgcn_sched_barrier(0);
        cur = (cur == 2) ? 0 : cur + 1;
    }

#pragma unroll
    for (int m = 0; m < 2; ++m) {
        float lt = lsum[m] + __shfl_xor(lsum[m], 16);
        lt += __shfl_xor(lt, 32);
        float inv[4];
#pragma unroll
        for (int q = 0; q < 4; ++q)
            inv[q] = 1.f / __shfl(lt, g * 4 + q);
#pragma unroll
        for (int n = 0; n < 4; ++n)
#pragma unroll
            for (int q = 0; q < 4; ++q) {
                size_t tok = (size_t)b * 1024 + s0 + w * 32 + m * 16 + g * 4 + q;
                Og[tok * 1024 + h * 64 + n * 16 + c] = f2b(oacc[m][n][q] * inv[q]);
            }
    }
}

// ---------------------------------------------------------------------------
// LayerNorm (bf16 I/O, fp32 math): pf <- LN(Yr)*g + b (residual pre-fused)
// ---------------------------------------------------------------------------
__global__ __launch_bounds__(256) void ln_k(
    const u16* __restrict__ Yr, u16* __restrict__ Pf,
    const float* __restrict__ g, const float* __restrict__ bt)
{
    const int rw = blockIdx.x;
    const int tid = threadIdx.x;
    const u16* yp = Yr + (size_t)rw * M_ + tid * 4;
    u16* pp = Pf + (size_t)rw * M_ + tid * 4;
    ushort4 yv = *(const ushort4*)yp;
    float a[4];
    a[0] = b2f(yv.x); a[1] = b2f(yv.y);
    a[2] = b2f(yv.z); a[3] = b2f(yv.w);
    float s = a[0] + a[1] + a[2] + a[3];
    float q = a[0] * a[0] + a[1] * a[1] + a[2] * a[2] + a[3] * a[3];
#pragma unroll
    for (int o = 1; o < 64; o <<= 1) {
        s += __shfl_xor(s, o);
        q += __shfl_xor(q, o);
    }
    __shared__ float ss[4], qq[4];
    if ((tid & 63) == 0) { ss[tid >> 6] = s; qq[tid >> 6] = q; }
    __syncthreads();
    s = ss[0] + ss[1] + ss[2] + ss[3];
    q = qq[0] + qq[1] + qq[2] + qq[3];
    float mu = s * (1.0f / 1024.0f);
    float var = q * (1.0f / 1024.0f) - mu * mu;
    float inv = rsqrtf(var + 1e-5f);
    float4 gv = *(const float4*)(g + (tid << 2));
    float4 bv = *(const float4*)(bt + (tid << 2));
    *(ushort4*)pp = make_ushort4(
        f2b((a[0] - mu) * inv * gv.x + bv.x),
        f2b((a[1] - mu) * inv * gv.y + bv.y),
        f2b((a[2] - mu) * inv * gv.z + bv.z),
        f2b((a[3] - mu) * inv * gv.w + bv.w));
}

// ---------------------------------------------------------------------------
extern "C" void kernel_launch(void* const* d_in, const int* in_sizes, int n_in,
                              void* d_out, int out_size, void* d_ws, size_t ws_size,
                              hipStream_t stream)
{
    const float* x     = (const float*)d_in[0];
    const float* Wemb  = (const float*)d_in[1];
    const float* bemb  = (const float*)d_in[2];
    // d_in[3]=Wamp, d_in[4]=bamp dead (mean of softmax = 1/F)
    const float* freqs = (const float*)d_in[5];
    const float* poff  = (const float*)d_in[6];
    const float* Wq    = (const float*)d_in[7];
    const float* bq    = (const float*)d_in[8];
    const float* Wk    = (const float*)d_in[9];
    const float* bk    = (const float*)d_in[10];
    const float* Wv    = (const float*)d_in[11];
    const float* bv    = (const float*)d_in[12];
    const float* Wo    = (const float*)d_in[13];
    const float* bo    = (const float*)d_in[14];
    const float* pbias = (const float*)d_in[15];
    const float* lng   = (const float*)d_in[16];
    const float* lnb   = (const float*)d_in[17];
    const float* W1    = (const float*)d_in[18];
    const float* b1    = (const float*)d_in[19];
    const float* W2    = (const float*)d_in[20];
    const float* b2    = (const float*)d_in[21];
    float* out = (float*)d_out;

    char* ws = (char*)d_ws;
    const size_t MB = 1 << 20;
    u16* pf    = (u16*)(ws);                            // 4096x1024   8MB
    u16* QKV   = (u16*)(ws + 8 * MB);                   // 4096x3072  24MB (also Yr)
    u16* Ab    = (u16*)(ws + 32 * MB);                  // 4096x1024   8MB (also hdn)
    u16* Vtg   = (u16*)(ws + 40 * MB);                  // [bh*64+d][1024] 8MB
    u16* WqkvT = (u16*)(ws + 48 * MB);                  // 2x 3072x1024 12MB
    u16* WoT   = (u16*)(ws + 60 * MB);                  // 2x 1024x1024  4MB
    u16* WembT = (u16*)(ws + 64 * MB);                  // 1024x256   0.5MB
    u16* W1T   = (u16*)(ws + 64 * MB + 512 * 1024);     // 512x1024     1MB
    u16* W2T   = (u16*)(ws + 65 * MB + 512 * 1024);     // 256x512   0.25MB
    u16* xb    = (u16*)(ws + 66 * MB);                  // 4096x256     2MB
    u16* qcs   = (u16*)(ws + 68 * MB);                  // 2x16x1024x16 1MB
    u16* csb   = (u16*)(ws + 69 * MB);                  // 1024x16    32KB
    float* bqkv = (float*)(ws + 69 * MB + 64 * 1024);   // 2x3072 f32 24KB

    dim3 blk(256);
    prep_k<<<10168, blk, 0, stream>>>(x, Wemb, Wq, Wk, Wv, Wo, W1, W2,
                                      freqs, poff, pbias, bq, bk, bv,
                                      xb, WembT, WqkvT, WoT, W1T, W2T,
                                      qcs, csb, bqkv);

    // pf = |x @ Wemb + bemb| * 0.125   (BM=64: grid 8x64 = 2 blocks/CU)
    mgemm_k<1, 1, 64><<<dim3(8, 64), blk, 0, stream>>>(xb, WembT, bemb, pf, nullptr, 1024, 256);

    for (int l = 0; l < L_; ++l) {
        // fused QKV projection: 256^2 tile, BK=32 ring-3 counted-vmcnt pipeline
        qkv256_k<<<dim3(192), dim3(512), 0, stream>>>(
            pf, WqkvT + (size_t)l * 3072 * 1024, bqkv + l * 3072, QKV, Vtg);
        fattn_k<<<dim3(512), blk, 0, stream>>>(
            QKV, Vtg, csb, qcs + (size_t)l * H_ * S_ * 16, Ab);
        // Wo projection + residual add fused (BM=64: grid 8x64 = 2 blocks/CU)
        mgemm_k<6, 1, 64><<<dim3(8, 64), blk, 0, stream>>>(
            Ab, WoT + (size_t)l * M_ * M_, bo + l * M_, QKV /*Yr*/, pf, 1024, 1024);
        ln_k<<<dim3(NT_), blk, 0, stream>>>(QKV, pf, lng + l * M_, lnb + l * M_);
    }

    // hdn = relu(pf @ W1 + b1) -> Ab ; out = hdn @ W2 + b2 (fp32)
    mgemm_k<2, 1, 64><<<dim3(4, 64), blk, 0, stream>>>(pf, W1T, b1, Ab, nullptr, 512, 1024);
    mgemm_k<0, 0, 64><<<dim3(2, 64), blk, 0, stream>>>(Ab, W2T, b2, out, nullptr, 256, 512);
}

// Round 10
// 235.747 us; speedup vs baseline: 1.0999x; 1.0999x over previous
//
#include <hip/hip_runtime.h>
#include <cmath>

#define B_    4
#define S_    1024
#define DIN_  256
#define M_    1024
#define H_    16
#define F_    8
#define L_    2
#define DOUT_ 256
#define NT_   4096   // B*S tokens

typedef unsigned short u16;
typedef unsigned int   u32;
typedef __bf16 bf16x8 __attribute__((ext_vector_type(8)));
typedef __bf16 bf16x4v __attribute__((ext_vector_type(4)));
typedef float  f32x4  __attribute__((ext_vector_type(4)));

#define LOG2E 1.4426950408889634f
#define QSCALE (0.125f * LOG2E)

__device__ __forceinline__ u16 f2b(float f) {
    u32 u = __builtin_bit_cast(u32, f);
    u += 0x7fffu + ((u >> 16) & 1u);
    return (u16)(u >> 16);
}
__device__ __forceinline__ float b2f(u32 h) {
    return __builtin_bit_cast(float, h << 16);
}
// async global->LDS, 16B per lane; LDS dest must be wave-uniform base (+lane*16 by HW)
__device__ __forceinline__ void gload_lds16(const void* g, void* l) {
    __builtin_amdgcn_global_load_lds(
        (const __attribute__((address_space(1))) u32*)g,
        (__attribute__((address_space(3))) u32*)l, 16, 0, 0);
}

// ---------------------------------------------------------------------------
// Unified prep kernel. One sincosf per (s,f), broadcast over 32 (l,h) rows.
// ---------------------------------------------------------------------------
__device__ __forceinline__ void tileT(float (*t)[33], const float* src,
                                      u16* dst, int K, int N, int n0, int k0,
                                      int tid)
{
    const int r = tid >> 3, c4 = (tid & 7) << 2;
    float4 v = *(const float4*)(src + (size_t)(k0 + r) * N + n0 + c4);
    t[r][c4 + 0] = v.x; t[r][c4 + 1] = v.y; t[r][c4 + 2] = v.z; t[r][c4 + 3] = v.w;
    __syncthreads();
    ushort4 o = make_ushort4(f2b(t[c4 + 0][r]), f2b(t[c4 + 1][r]),
                             f2b(t[c4 + 2][r]), f2b(t[c4 + 3][r]));
    *(ushort4*)(dst + (size_t)(n0 + r) * K + k0 + c4) = o;
}

__global__ __launch_bounds__(256) void prep_k(
    const float* __restrict__ x, const float* __restrict__ Wemb,
    const float* __restrict__ Wq, const float* __restrict__ Wk,
    const float* __restrict__ Wv, const float* __restrict__ Wo,
    const float* __restrict__ W1, const float* __restrict__ W2,
    const float* __restrict__ freqs, const float* __restrict__ poff,
    const float* __restrict__ pb, const float* __restrict__ bq,
    const float* __restrict__ bk, const float* __restrict__ bv,
    u16* __restrict__ xb, u16* __restrict__ WembT, u16* __restrict__ WqkvT,
    u16* __restrict__ WoT, u16* __restrict__ W1T, u16* __restrict__ W2T,
    u16* __restrict__ qcs, u16* __restrict__ csb, float* __restrict__ bqkv)
{
    __shared__ float t[32][33];
    const int bid = blockIdx.x, tid = threadIdx.x;

    if (bid < 1024) {                       // x -> bf16
        int i = (bid * 256 + tid) * 4;
        float4 v = *(const float4*)(x + i);
        *(ushort4*)(xb + i) = make_ushort4(f2b(v.x), f2b(v.y), f2b(v.z), f2b(v.w));
    } else if (bid < 7168) {                // WqkvT
        int id = bid - 1024;
        int z = id >> 10, rem = id & 1023;
        int n0 = (rem & 31) << 5, k0 = (rem >> 5) << 5;
        int l = z / 3, which = z - l * 3;
        const float* src = (which == 0 ? Wq : which == 1 ? Wk : Wv) + (size_t)l * M_ * M_;
        u16* d = WqkvT + (size_t)l * 3072 * 1024 + (size_t)which * 1024 * 1024;
        tileT(t, src, d, 1024, 1024, n0, k0, tid);
    } else if (bid < 9216) {                // WoT
        int id = bid - 7168;
        int z = id >> 10, rem = id & 1023;
        int n0 = (rem & 31) << 5, k0 = (rem >> 5) << 5;
        tileT(t, Wo + (size_t)z * M_ * M_, WoT + (size_t)z * M_ * M_,
              1024, 1024, n0, k0, tid);
    } else if (bid < 9472) {                // WembT (K=256, N=1024)
        int id = bid - 9216;
        int n0 = (id & 31) << 5, k0 = (id >> 5) << 5;
        tileT(t, Wemb, WembT, 256, 1024, n0, k0, tid);
    } else if (bid < 9984) {                // W1T (K=1024, N=512)
        int id = bid - 9472;
        int n0 = (id & 15) << 5, k0 = (id >> 4) << 5;
        tileT(t, W1, W1T, 1024, 512, n0, k0, tid);
    } else if (bid < 10112) {               // W2T (K=512, N=256)
        int id = bid - 9984;
        int n0 = (id & 7) << 5, k0 = (id >> 3) << 5;
        tileT(t, W2, W2T, 512, 256, n0, k0, tid);
    } else if (bid < 10144) {               // csb + qcs tables (1 sincos/(s,f))
        int idx = (bid - 10112) * 256 + tid;   // 0..8191 = s*8 + f
        int s = idx >> 3, f = idx & 7;
        float pc = ((float)s * (6.283185307179586f / 1024.f)) * freqs[f] + poff[f];
        float sn, cs;
        __sincosf(pc, &sn, &cs);
        csb[s * 16 + f] = f2b(cs);
        csb[s * 16 + f + 8] = f2b(sn);
#pragma unroll
        for (int lh = 0; lh < 32; ++lh) {
            float p = pb[lh * 8 + f] * LOG2E;
            qcs[lh * 16384 + s * 16 + f] = f2b(p * cs);
            qcs[lh * 16384 + s * 16 + f + 8] = f2b(p * sn);
        }
    } else {                                // bias concat
        int idx = (bid - 10144) * 256 + tid;   // 0..6143
        int l = idx >= 3072;
        int j = idx - l * 3072;
        float v = (j < 1024) ? bq[l * 1024 + j]
                : (j < 2048) ? bk[l * 1024 + j - 1024]
                             : bv[l * 1024 + j - 2048];
        bqkv[idx] = v;
    }
}

// ---------------------------------------------------------------------------
// bf16 MFMA GEMM (proven 128/64-row structure) + XCD-bijective 1D grid:
// swz = (bid%8)*(nwg/8) + bid/8 (nwg always %8==0) -> consecutive same-XCD
// blocks share the A-panel (L2-resident per XCD).
// EPI: 0 none, 1 |c|*0.125, 2 relu,
//      5 fused-QKV (BM=128): cols<1024 *QSCALE; cols>=2048 (V) written ONLY
//        transposed into vt; 6: +residual from vt (bf16) fused (Wo epilogue).
// ---------------------------------------------------------------------------
template<int EPI, int OUTBF, int BM>
__global__ __launch_bounds__(256, 2) void mgemm_k(
    const u16* __restrict__ A, const u16* __restrict__ Wt,
    const float* __restrict__ bias, void* __restrict__ Cout,
    u16* __restrict__ vt, int N, int K, int nbn)
{
    constexpr int MR = BM / 32;             // m-frags per wave
    __shared__ __attribute__((aligned(16))) u16 As[BM * 64];
    __shared__ __attribute__((aligned(16))) u16 Bs[128 * 64];
    const int tid = threadIdx.x;
    const int lane = tid & 63;
    // XCD-bijective swizzle (gridDim.x % 8 == 0 for all our launches)
    const int bid = blockIdx.x, q8 = gridDim.x >> 3;
    const int swz = (bid & 7) * q8 + (bid >> 3);
    const int bn = swz % nbn, bm = swz / nbn;
    const int wid = tid >> 6, wr = wid >> 1, wc = wid & 1;

    f32x4 acc[MR][4];
#pragma unroll
    for (int m = 0; m < MR; ++m)
#pragma unroll
        for (int n = 0; n < 4; ++n) {
            f32x4 z = {0.f, 0.f, 0.f, 0.f};
            acc[m][n] = z;
        }

    const int r = lane & 15, g = lane >> 4;
    const int nk = K >> 6;

    for (int kt = 0; kt < nk; ++kt) {
        const int k0 = kt << 6;
        __syncthreads();
#pragma unroll
        for (int i = 0; i < (BM >> 5); ++i) {
            int slot = i * 256 + tid;
            int row = slot >> 3;
            int kg = (slot & 7) ^ (row & 7);
            gload_lds16(A + (size_t)(bm * BM + row) * K + k0 + kg * 8,
                        As + (size_t)(slot & ~63) * 8);
        }
#pragma unroll
        for (int i = 0; i < 4; ++i) {
            int slot = i * 256 + tid;
            int row = slot >> 3;
            int kg = (slot & 7) ^ (row & 7);
            gload_lds16(Wt + (size_t)(bn * 128 + row) * K + k0 + kg * 8,
                        Bs + (size_t)(slot & ~63) * 8);
        }
        __syncthreads();

#pragma unroll
        for (int ks = 0; ks < 2; ++ks) {
            bf16x8 af[MR], bfr[4];
#pragma unroll
            for (int m = 0; m < MR; ++m) {
                int row = wr * (BM >> 1) + m * 16 + r;
                int kg = (ks * 4 + g) ^ (row & 7);
                af[m] = *(const bf16x8*)(As + row * 64 + kg * 8);
            }
#pragma unroll
            for (int n = 0; n < 4; ++n) {
                int row = wc * 64 + n * 16 + r;
                int kg = (ks * 4 + g) ^ (row & 7);
                bfr[n] = *(const bf16x8*)(Bs + row * 64 + kg * 8);
            }
#pragma unroll
            for (int m = 0; m < MR; ++m)
#pragma unroll
                for (int n = 0; n < 4; ++n)
                    acc[m][n] = __builtin_amdgcn_mfma_f32_16x16x32_bf16(
                        af[m], bfr[n], acc[m][n], 0, 0, 0);
        }
    }

#pragma unroll
    for (int n = 0; n < 4; ++n) {
        const int gcol = bn * 128 + wc * 64 + n * 16 + r;
        const float bb = bias[gcol];
#pragma unroll
        for (int m = 0; m < MR; ++m) {
            const int grow0 = bm * BM + wr * (BM >> 1) + m * 16 + g * 4;
            if (EPI == 5 && gcol >= 2048) {
                // V^T write only: d = gcol-2048, token rows are consecutive q
                int d = gcol - 2048;
                int bh = (grow0 >> 10) * 16 + (d >> 6);
                u16 pk[4];
#pragma unroll
                for (int q = 0; q < 4; ++q) pk[q] = f2b(acc[m][n][q] + bb);
                uint2 pv;
                pv.x = (u32)pk[0] | ((u32)pk[1] << 16);
                pv.y = (u32)pk[2] | ((u32)pk[3] << 16);
                *(uint2*)(vt + ((size_t)bh * 64 + (d & 63)) * 1024 + (grow0 & 1023)) = pv;
            } else {
#pragma unroll
                for (int q = 0; q < 4; ++q) {
                    float c = acc[m][n][q] + bb;
                    if (EPI == 1) c = fabsf(c) * 0.125f;
                    if (EPI == 2) c = fmaxf(c, 0.f);
                    if (EPI == 5) c = (gcol < 1024) ? c * QSCALE : c;
                    if (EPI == 6)
                        c += b2f(vt[(size_t)(grow0 + q) * N + gcol]);  // residual
                    if (OUTBF)
                        ((u16*)Cout)[(size_t)(grow0 + q) * N + gcol] = f2b(c);
                    else
                        ((float*)Cout)[(size_t)(grow0 + q) * N + gcol] = c;
                }
            }
        }
    }
}

// ---------------------------------------------------------------------------
// MFMA flash attention (unchanged): 3-deep prefetch, counted vmcnt,
// XCD-colocated grid, no-max exp2 softmax, swapped QK^T, 4 waves x 32q.
// ---------------------------------------------------------------------------
__global__ __launch_bounds__(256) void fattn_k(
    const u16* __restrict__ QKV, const u16* __restrict__ Vtg,
    const u16* __restrict__ csb, const u16* __restrict__ qcs,
    u16* __restrict__ Og)
{
    __shared__ __attribute__((aligned(16))) u16 Ks3[3][64 * 64];
    __shared__ __attribute__((aligned(16))) u16 Vt3[3][64 * 64];
    __shared__ __attribute__((aligned(16))) u16 Ext[3][64 * 16];
    __shared__ __attribute__((aligned(16))) u16 Pl[4][32 * 68];
    const int tid = threadIdx.x, lane = tid & 63, w = tid >> 6;
    const int c = lane & 15, g = lane >> 4;
    const int Lid = blockIdx.x;
    const int slot = Lid >> 3;
    const int grp = (Lid & 7) * 8 + (slot >> 3);      // (b*16+h)
    const int qi = slot & 7;
    const int b = grp >> 4, h = grp & 15, bh = grp;
    const int s0 = qi * 128;

    const uint4 zz = {0u, 0u, 0u, 0u};
    const bf16x8 zfrag = __builtin_bit_cast(bf16x8, zz);

    bf16x8 aq[2][3];
#pragma unroll
    for (int m = 0; m < 2; ++m) {
        int sl = s0 + w * 32 + m * 16 + c;
        size_t tok = (size_t)b * 1024 + sl;
        aq[m][0] = *(const bf16x8*)(QKV + tok * 3072 + h * 64 + g * 8);
        aq[m][1] = *(const bf16x8*)(QKV + tok * 3072 + h * 64 + 32 + g * 8);
        aq[m][2] = (g < 2) ? *(const bf16x8*)(qcs + ((size_t)h * 1024 + sl) * 16 + g * 8)
                           : zfrag;
    }
    __builtin_amdgcn_sched_barrier(0);

    f32x4 oacc[2][4];
#pragma unroll
    for (int m = 0; m < 2; ++m)
#pragma unroll
        for (int n = 0; n < 4; ++n) {
            f32x4 z = {0.f, 0.f, 0.f, 0.f};
            oacc[m][n] = z;
        }
    float lsum[2] = {0.f, 0.f};

    auto STAGE = [&](int buf, int t0) {
#pragma unroll
        for (int i = 0; i < 2; ++i) {
            int sl2 = i * 256 + tid;
            int row = sl2 >> 3, gi = sl2 & 7;
            int kg = (gi ^ (row & 7)) * 8;
            gload_lds16(QKV + (size_t)(b * 1024 + t0 + row) * 3072 + 1024 + h * 64 + kg,
                        &Ks3[buf][(size_t)(sl2 & ~63) * 8]);
            gload_lds16(Vtg + (size_t)(bh * 64 + row) * 1024 + t0 + kg,
                        &Vt3[buf][(size_t)(sl2 & ~63) * 8]);
        }
        if (tid < 128) {
            int r2 = tid >> 1, g2 = tid & 1;
            gload_lds16(csb + (size_t)(t0 + r2) * 16 + g2 * 8,
                        &Ext[buf][(size_t)(tid & ~63) * 8]);
        }
    };

    STAGE(0, 0);
    STAGE(1, 64);
    __builtin_amdgcn_sched_barrier(0);

    int cur = 0;
    for (int it = 0; it < 16; ++it) {
        if (it < 14) {
            int nb = cur + 2; if (nb >= 3) nb -= 3;
            STAGE(nb, (it + 2) << 6);
            if (w < 2) asm volatile("s_waitcnt vmcnt(10)" ::: "memory");
            else       asm volatile("s_waitcnt vmcnt(8)" ::: "memory");
        } else if (it == 14) {
            if (w < 2) asm volatile("s_waitcnt vmcnt(5)" ::: "memory");
            else       asm volatile("s_waitcnt vmcnt(4)" ::: "memory");
        } else {
            asm volatile("s_waitcnt vmcnt(0)" ::: "memory");
        }
        __builtin_amdgcn_sched_barrier(0);
        __builtin_amdgcn_s_barrier();
        __builtin_amdgcn_sched_barrier(0);

        const u16* ksb = &Ks3[cur][0];
        const u16* vtb = &Vt3[cur][0];
        const u16* exb = &Ext[cur][0];

        f32x4 sacc[2][4];
#pragma unroll
        for (int m = 0; m < 2; ++m)
#pragma unroll
            for (int n = 0; n < 4; ++n) {
                f32x4 z = {0.f, 0.f, 0.f, 0.f};
                sacc[m][n] = z;
            }
        __builtin_amdgcn_s_setprio(1);
#pragma unroll
        for (int ks = 0; ks < 3; ++ks) {
            bf16x8 bk[4];
#pragma unroll
            for (int n = 0; n < 4; ++n) {
                int tr = n * 16 + c;
                if (ks < 2) {
                    int kg = (ks * 4 + g) ^ (tr & 7);
                    bk[n] = *(const bf16x8*)(ksb + tr * 64 + kg * 8);
                } else {
                    bk[n] = (g < 2) ? *(const bf16x8*)(exb + tr * 16 + g * 8) : zfrag;
                }
            }
#pragma unroll
            for (int n = 0; n < 4; ++n)
#pragma unroll
                for (int m = 0; m < 2; ++m)
                    sacc[m][n] = __builtin_amdgcn_mfma_f32_16x16x32_bf16(
                        bk[n], aq[m][ks], sacc[m][n], 0, 0, 0);
        }
        __builtin_amdgcn_s_setprio(0);

#pragma unroll
        for (int m = 0; m < 2; ++m)
#pragma unroll
            for (int n = 0; n < 4; ++n) {
                float p0 = __builtin_amdgcn_exp2f(sacc[m][n][0]);
                float p1 = __builtin_amdgcn_exp2f(sacc[m][n][1]);
                float p2 = __builtin_amdgcn_exp2f(sacc[m][n][2]);
                float p3 = __builtin_amdgcn_exp2f(sacc[m][n][3]);
                lsum[m] += (p0 + p1) + (p2 + p3);
                bf16x4v pk;
                pk[0] = (__bf16)p0; pk[1] = (__bf16)p1;
                pk[2] = (__bf16)p2; pk[3] = (__bf16)p3;
                *(bf16x4v*)(&Pl[w][(m * 16 + c) * 68 + n * 16 + g * 4]) = pk;
            }

        __builtin_amdgcn_s_setprio(1);
#pragma unroll
        for (int ks2 = 0; ks2 < 2; ++ks2) {
            bf16x8 pa[2];
#pragma unroll
            for (int m = 0; m < 2; ++m)
                pa[m] = *(const bf16x8*)(&Pl[w][(m * 16 + c) * 68 + ks2 * 32 + g * 8]);
#pragma unroll
            for (int n = 0; n < 4; ++n) {
                int dr = n * 16 + c;
                int kg = (ks2 * 4 + g) ^ (dr & 7);
                bf16x8 vf = *(const bf16x8*)(vtb + dr * 64 + kg * 8);
#pragma unroll
                for (int m = 0; m < 2; ++m)
                    oacc[m][n] = __builtin_amdgcn_mfma_f32_16x16x32_bf16(
                        pa[m], vf, oacc[m][n], 0, 0, 0);
            }
        }
        __builtin_amdgcn_s_setprio(0);

        __builtin_amdgcn_sched_barrier(0);
        __builtin_amdgcn_s_barrier();
        __builtin_amdgcn_sched_barrier(0);
        cur = (cur == 2) ? 0 : cur + 1;
    }

#pragma unroll
    for (int m = 0; m < 2; ++m) {
        float lt = lsum[m] + __shfl_xor(lsum[m], 16);
        lt += __shfl_xor(lt, 32);
        float inv[4];
#pragma unroll
        for (int q = 0; q < 4; ++q)
            inv[q] = 1.f / __shfl(lt, g * 4 + q);
#pragma unroll
        for (int n = 0; n < 4; ++n)
#pragma unroll
            for (int q = 0; q < 4; ++q) {
                size_t tok = (size_t)b * 1024 + s0 + w * 32 + m * 16 + g * 4 + q;
                Og[tok * 1024 + h * 64 + n * 16 + c] = f2b(oacc[m][n][q] * inv[q]);
            }
    }
}

// ---------------------------------------------------------------------------
// LayerNorm (bf16 I/O, fp32 math): pf <- LN(Yr)*g + b (residual pre-fused)
// ---------------------------------------------------------------------------
__global__ __launch_bounds__(256) void ln_k(
    const u16* __restrict__ Yr, u16* __restrict__ Pf,
    const float* __restrict__ g, const float* __restrict__ bt)
{
    const int rw = blockIdx.x;
    const int tid = threadIdx.x;
    const u16* yp = Yr + (size_t)rw * M_ + tid * 4;
    u16* pp = Pf + (size_t)rw * M_ + tid * 4;
    ushort4 yv = *(const ushort4*)yp;
    float a[4];
    a[0] = b2f(yv.x); a[1] = b2f(yv.y);
    a[2] = b2f(yv.z); a[3] = b2f(yv.w);
    float s = a[0] + a[1] + a[2] + a[3];
    float q = a[0] * a[0] + a[1] * a[1] + a[2] * a[2] + a[3] * a[3];
#pragma unroll
    for (int o = 1; o < 64; o <<= 1) {
        s += __shfl_xor(s, o);
        q += __shfl_xor(q, o);
    }
    __shared__ float ss[4], qq[4];
    if ((tid & 63) == 0) { ss[tid >> 6] = s; qq[tid >> 6] = q; }
    __syncthreads();
    s = ss[0] + ss[1] + ss[2] + ss[3];
    q = qq[0] + qq[1] + qq[2] + qq[3];
    float mu = s * (1.0f / 1024.0f);
    float var = q * (1.0f / 1024.0f) - mu * mu;
    float inv = rsqrtf(var + 1e-5f);
    float4 gv = *(const float4*)(g + (tid << 2));
    float4 bv = *(const float4*)(bt + (tid << 2));
    *(ushort4*)pp = make_ushort4(
        f2b((a[0] - mu) * inv * gv.x + bv.x),
        f2b((a[1] - mu) * inv * gv.y + bv.y),
        f2b((a[2] - mu) * inv * gv.z + bv.z),
        f2b((a[3] - mu) * inv * gv.w + bv.w));
}

// ---------------------------------------------------------------------------
extern "C" void kernel_launch(void* const* d_in, const int* in_sizes, int n_in,
                              void* d_out, int out_size, void* d_ws, size_t ws_size,
                              hipStream_t stream)
{
    const float* x     = (const float*)d_in[0];
    const float* Wemb  = (const float*)d_in[1];
    const float* bemb  = (const float*)d_in[2];
    // d_in[3]=Wamp, d_in[4]=bamp dead (mean of softmax = 1/F)
    const float* freqs = (const float*)d_in[5];
    const float* poff  = (const float*)d_in[6];
    const float* Wq    = (const float*)d_in[7];
    const float* bq    = (const float*)d_in[8];
    const float* Wk    = (const float*)d_in[9];
    const float* bk    = (const float*)d_in[10];
    const float* Wv    = (const float*)d_in[11];
    const float* bv    = (const float*)d_in[12];
    const float* Wo    = (const float*)d_in[13];
    const float* bo    = (const float*)d_in[14];
    const float* pbias = (const float*)d_in[15];
    const float* lng   = (const float*)d_in[16];
    const float* lnb   = (const float*)d_in[17];
    const float* W1    = (const float*)d_in[18];
    const float* b1    = (const float*)d_in[19];
    const float* W2    = (const float*)d_in[20];
    const float* b2    = (const float*)d_in[21];
    float* out = (float*)d_out;

    char* ws = (char*)d_ws;
    const size_t MB = 1 << 20;
    u16* pf    = (u16*)(ws);                            // 4096x1024   8MB
    u16* QKV   = (u16*)(ws + 8 * MB);                   // 4096x3072  24MB (also Yr)
    u16* Ab    = (u16*)(ws + 32 * MB);                  // 4096x1024   8MB (also hdn)
    u16* Vtg   = (u16*)(ws + 40 * MB);                  // [bh*64+d][1024] 8MB
    u16* WqkvT = (u16*)(ws + 48 * MB);                  // 2x 3072x1024 12MB
    u16* WoT   = (u16*)(ws + 60 * MB);                  // 2x 1024x1024  4MB
    u16* WembT = (u16*)(ws + 64 * MB);                  // 1024x256   0.5MB
    u16* W1T   = (u16*)(ws + 64 * MB + 512 * 1024);     // 512x1024     1MB
    u16* W2T   = (u16*)(ws + 65 * MB + 512 * 1024);     // 256x512   0.25MB
    u16* xb    = (u16*)(ws + 66 * MB);                  // 4096x256     2MB
    u16* qcs   = (u16*)(ws + 68 * MB);                  // 2x16x1024x16 1MB
    u16* csb   = (u16*)(ws + 69 * MB);                  // 1024x16    32KB
    float* bqkv = (float*)(ws + 69 * MB + 64 * 1024);   // 2x3072 f32 24KB

    dim3 blk(256);
    prep_k<<<10168, blk, 0, stream>>>(x, Wemb, Wq, Wk, Wv, Wo, W1, W2,
                                      freqs, poff, pbias, bq, bk, bv,
                                      xb, WembT, WqkvT, WoT, W1T, W2T,
                                      qcs, csb, bqkv);

    // pf = |x @ Wemb + bemb| * 0.125   (nbn=8, 512 blocks)
    mgemm_k<1, 1, 64><<<dim3(512), blk, 0, stream>>>(
        xb, WembT, bemb, pf, nullptr, 1024, 256, 8);

    for (int l = 0; l < L_; ++l) {
        // fused QKV projection (Q pre-scaled; V written directly transposed)
        mgemm_k<5, 1, 128><<<dim3(768), blk, 0, stream>>>(
            pf, WqkvT + (size_t)l * 3072 * 1024, bqkv + l * 3072, QKV, Vtg,
            3072, 1024, 24);
        fattn_k<<<dim3(512), blk, 0, stream>>>(
            QKV, Vtg, csb, qcs + (size_t)l * H_ * S_ * 16, Ab);
        // Wo projection + residual add fused
        mgemm_k<6, 1, 64><<<dim3(512), blk, 0, stream>>>(
            Ab, WoT + (size_t)l * M_ * M_, bo + l * M_, QKV /*Yr*/, pf,
            1024, 1024, 8);
        ln_k<<<dim3(NT_), blk, 0, stream>>>(QKV, pf, lng + l * M_, lnb + l * M_);
    }

    // hdn = relu(pf @ W1 + b1) -> Ab ; out = hdn @ W2 + b2 (fp32)
    mgemm_k<2, 1, 64><<<dim3(256), blk, 0, stream>>>(
        pf, W1T, b1, Ab, nullptr, 512, 1024, 4);
    mgemm_k<0, 0, 64><<<dim3(128), blk, 0, stream>>>(
        Ab, W2T, b2, out, nullptr, 256, 512, 2);
}

// Round 11
// 235.536 us; speedup vs baseline: 1.1008x; 1.0009x over previous
//
#include <hip/hip_runtime.h>
#include <cmath>

#define B_    4
#define S_    1024
#define DIN_  256
#define M_    1024
#define H_    16
#define F_    8
#define L_    2
#define DOUT_ 256
#define NT_   4096   // B*S tokens

typedef unsigned short u16;
typedef unsigned int   u32;
typedef __bf16 bf16x8 __attribute__((ext_vector_type(8)));
typedef __bf16 bf16x4v __attribute__((ext_vector_type(4)));
typedef float  f32x4  __attribute__((ext_vector_type(4)));

#define LOG2E 1.4426950408889634f
#define QSCALE (0.125f * LOG2E)

__device__ __forceinline__ u16 f2b(float f) {
    u32 u = __builtin_bit_cast(u32, f);
    u += 0x7fffu + ((u >> 16) & 1u);
    return (u16)(u >> 16);
}
__device__ __forceinline__ float b2f(u32 h) {
    return __builtin_bit_cast(float, h << 16);
}
// async global->LDS, 16B per lane; LDS dest must be wave-uniform base (+lane*16 by HW)
__device__ __forceinline__ void gload_lds16(const void* g, void* l) {
    __builtin_amdgcn_global_load_lds(
        (const __attribute__((address_space(1))) u32*)g,
        (__attribute__((address_space(3))) u32*)l, 16, 0, 0);
}

// ---------------------------------------------------------------------------
// Unified prep kernel. One sincosf per (s,f), broadcast over 32 (l,h) rows.
// ---------------------------------------------------------------------------
__device__ __forceinline__ void tileT(float (*t)[33], const float* src,
                                      u16* dst, int K, int N, int n0, int k0,
                                      int tid)
{
    const int r = tid >> 3, c4 = (tid & 7) << 2;
    float4 v = *(const float4*)(src + (size_t)(k0 + r) * N + n0 + c4);
    t[r][c4 + 0] = v.x; t[r][c4 + 1] = v.y; t[r][c4 + 2] = v.z; t[r][c4 + 3] = v.w;
    __syncthreads();
    ushort4 o = make_ushort4(f2b(t[c4 + 0][r]), f2b(t[c4 + 1][r]),
                             f2b(t[c4 + 2][r]), f2b(t[c4 + 3][r]));
    *(ushort4*)(dst + (size_t)(n0 + r) * K + k0 + c4) = o;
}

__global__ __launch_bounds__(256) void prep_k(
    const float* __restrict__ x, const float* __restrict__ Wemb,
    const float* __restrict__ Wq, const float* __restrict__ Wk,
    const float* __restrict__ Wv, const float* __restrict__ Wo,
    const float* __restrict__ W1, const float* __restrict__ W2,
    const float* __restrict__ freqs, const float* __restrict__ poff,
    const float* __restrict__ pb, const float* __restrict__ bq,
    const float* __restrict__ bk, const float* __restrict__ bv,
    u16* __restrict__ xb, u16* __restrict__ WembT, u16* __restrict__ WqkvT,
    u16* __restrict__ WoT, u16* __restrict__ W1T, u16* __restrict__ W2T,
    u16* __restrict__ qcs, u16* __restrict__ csb, float* __restrict__ bqkv)
{
    __shared__ float t[32][33];
    const int bid = blockIdx.x, tid = threadIdx.x;

    if (bid < 1024) {                       // x -> bf16
        int i = (bid * 256 + tid) * 4;
        float4 v = *(const float4*)(x + i);
        *(ushort4*)(xb + i) = make_ushort4(f2b(v.x), f2b(v.y), f2b(v.z), f2b(v.w));
    } else if (bid < 7168) {                // WqkvT
        int id = bid - 1024;
        int z = id >> 10, rem = id & 1023;
        int n0 = (rem & 31) << 5, k0 = (rem >> 5) << 5;
        int l = z / 3, which = z - l * 3;
        const float* src = (which == 0 ? Wq : which == 1 ? Wk : Wv) + (size_t)l * M_ * M_;
        u16* d = WqkvT + (size_t)l * 3072 * 1024 + (size_t)which * 1024 * 1024;
        tileT(t, src, d, 1024, 1024, n0, k0, tid);
    } else if (bid < 9216) {                // WoT
        int id = bid - 7168;
        int z = id >> 10, rem = id & 1023;
        int n0 = (rem & 31) << 5, k0 = (rem >> 5) << 5;
        tileT(t, Wo + (size_t)z * M_ * M_, WoT + (size_t)z * M_ * M_,
              1024, 1024, n0, k0, tid);
    } else if (bid < 9472) {                // WembT (K=256, N=1024)
        int id = bid - 9216;
        int n0 = (id & 31) << 5, k0 = (id >> 5) << 5;
        tileT(t, Wemb, WembT, 256, 1024, n0, k0, tid);
    } else if (bid < 9984) {                // W1T (K=1024, N=512)
        int id = bid - 9472;
        int n0 = (id & 15) << 5, k0 = (id >> 4) << 5;
        tileT(t, W1, W1T, 1024, 512, n0, k0, tid);
    } else if (bid < 10112) {               // W2T (K=512, N=256)
        int id = bid - 9984;
        int n0 = (id & 7) << 5, k0 = (id >> 3) << 5;
        tileT(t, W2, W2T, 512, 256, n0, k0, tid);
    } else if (bid < 10144) {               // csb + qcs tables (1 sincos/(s,f))
        int idx = (bid - 10112) * 256 + tid;   // 0..8191 = s*8 + f
        int s = idx >> 3, f = idx & 7;
        float pc = ((float)s * (6.283185307179586f / 1024.f)) * freqs[f] + poff[f];
        float sn, cs;
        __sincosf(pc, &sn, &cs);
        csb[s * 16 + f] = f2b(cs);
        csb[s * 16 + f + 8] = f2b(sn);
#pragma unroll
        for (int lh = 0; lh < 32; ++lh) {
            float p = pb[lh * 8 + f] * LOG2E;
            qcs[lh * 16384 + s * 16 + f] = f2b(p * cs);
            qcs[lh * 16384 + s * 16 + f + 8] = f2b(p * sn);
        }
    } else {                                // bias concat
        int idx = (bid - 10144) * 256 + tid;   // 0..6143
        int l = idx >= 3072;
        int j = idx - l * 3072;
        float v = (j < 1024) ? bq[l * 1024 + j]
                : (j < 2048) ? bk[l * 1024 + j - 1024]
                             : bv[l * 1024 + j - 2048];
        bqkv[idx] = v;
    }
}

// ---------------------------------------------------------------------------
// bf16 MFMA GEMM (proven structure) + XCD-bijective 1D grid.
// BM in {128, 64, 32}. BM<128 declares min 4 waves/EU (4 blocks/CU) since
// those shapes are grid/latency-starved (acc small -> no spill at 128 VGPR).
// EPI: 0 none, 1 |c|*0.125, 2 relu,
//      5 fused-QKV (BM=128): cols<1024 *QSCALE; cols>=2048 (V) written ONLY
//        transposed into vt; 6: +residual from vt (bf16) fused (Wo epilogue).
// ---------------------------------------------------------------------------
template<int EPI, int OUTBF, int BM>
__global__ __launch_bounds__(256, (BM == 128) ? 2 : 4) void mgemm_k(
    const u16* __restrict__ A, const u16* __restrict__ Wt,
    const float* __restrict__ bias, void* __restrict__ Cout,
    u16* __restrict__ vt, int N, int K, int nbn)
{
    constexpr int MR = (BM + 31) / 32;      // m-frags per wave (128->4,64->2,32->1)
    __shared__ __attribute__((aligned(16))) u16 As[BM * 64];
    __shared__ __attribute__((aligned(16))) u16 Bs[128 * 64];
    const int tid = threadIdx.x;
    const int lane = tid & 63;
    // XCD-bijective swizzle (gridDim.x % 8 == 0 for all our launches)
    const int bid = blockIdx.x, q8 = gridDim.x >> 3;
    const int swz = (bid & 7) * q8 + (bid >> 3);
    const int bn = swz % nbn, bm = swz / nbn;
    const int wid = tid >> 6, wr = wid >> 1, wc = wid & 1;

    f32x4 acc[MR][4];
#pragma unroll
    for (int m = 0; m < MR; ++m)
#pragma unroll
        for (int n = 0; n < 4; ++n) {
            f32x4 z = {0.f, 0.f, 0.f, 0.f};
            acc[m][n] = z;
        }

    const int r = lane & 15, g = lane >> 4;
    const int nk = K >> 6;

    for (int kt = 0; kt < nk; ++kt) {
        const int k0 = kt << 6;
        __syncthreads();
#pragma unroll
        for (int i = 0; i < (BM >> 5); ++i) {
            int slot = i * 256 + tid;
            int row = slot >> 3;
            int kg = (slot & 7) ^ (row & 7);
            gload_lds16(A + (size_t)(bm * BM + row) * K + k0 + kg * 8,
                        As + (size_t)(slot & ~63) * 8);
        }
#pragma unroll
        for (int i = 0; i < 4; ++i) {
            int slot = i * 256 + tid;
            int row = slot >> 3;
            int kg = (slot & 7) ^ (row & 7);
            gload_lds16(Wt + (size_t)(bn * 128 + row) * K + k0 + kg * 8,
                        Bs + (size_t)(slot & ~63) * 8);
        }
        __syncthreads();

#pragma unroll
        for (int ks = 0; ks < 2; ++ks) {
            bf16x8 af[MR], bfr[4];
#pragma unroll
            for (int m = 0; m < MR; ++m) {
                int row = wr * (BM >> 1) + m * 16 + r;
                int kg = (ks * 4 + g) ^ (row & 7);
                af[m] = *(const bf16x8*)(As + row * 64 + kg * 8);
            }
#pragma unroll
            for (int n = 0; n < 4; ++n) {
                int row = wc * 64 + n * 16 + r;
                int kg = (ks * 4 + g) ^ (row & 7);
                bfr[n] = *(const bf16x8*)(Bs + row * 64 + kg * 8);
            }
#pragma unroll
            for (int m = 0; m < MR; ++m)
#pragma unroll
                for (int n = 0; n < 4; ++n)
                    acc[m][n] = __builtin_amdgcn_mfma_f32_16x16x32_bf16(
                        af[m], bfr[n], acc[m][n], 0, 0, 0);
        }
    }

#pragma unroll
    for (int n = 0; n < 4; ++n) {
        const int gcol = bn * 128 + wc * 64 + n * 16 + r;
        const float bb = bias[gcol];
#pragma unroll
        for (int m = 0; m < MR; ++m) {
            const int grow0 = bm * BM + wr * (BM >> 1) + m * 16 + g * 4;
            if (EPI == 5 && gcol >= 2048) {
                // V^T write only: d = gcol-2048, token rows are consecutive q
                int d = gcol - 2048;
                int bh = (grow0 >> 10) * 16 + (d >> 6);
                u16 pk[4];
#pragma unroll
                for (int q = 0; q < 4; ++q) pk[q] = f2b(acc[m][n][q] + bb);
                uint2 pv;
                pv.x = (u32)pk[0] | ((u32)pk[1] << 16);
                pv.y = (u32)pk[2] | ((u32)pk[3] << 16);
                *(uint2*)(vt + ((size_t)bh * 64 + (d & 63)) * 1024 + (grow0 & 1023)) = pv;
            } else {
#pragma unroll
                for (int q = 0; q < 4; ++q) {
                    float c = acc[m][n][q] + bb;
                    if (EPI == 1) c = fabsf(c) * 0.125f;
                    if (EPI == 2) c = fmaxf(c, 0.f);
                    if (EPI == 5) c = (gcol < 1024) ? c * QSCALE : c;
                    if (EPI == 6)
                        c += b2f(vt[(size_t)(grow0 + q) * N + gcol]);  // residual
                    if (OUTBF)
                        ((u16*)Cout)[(size_t)(grow0 + q) * N + gcol] = f2b(c);
                    else
                        ((float*)Cout)[(size_t)(grow0 + q) * N + gcol] = c;
                }
            }
        }
    }
}

// ---------------------------------------------------------------------------
// MFMA flash attention (unchanged): 3-deep prefetch, counted vmcnt,
// XCD-colocated grid, no-max exp2 softmax, swapped QK^T, 4 waves x 32q.
// ---------------------------------------------------------------------------
__global__ __launch_bounds__(256) void fattn_k(
    const u16* __restrict__ QKV, const u16* __restrict__ Vtg,
    const u16* __restrict__ csb, const u16* __restrict__ qcs,
    u16* __restrict__ Og)
{
    __shared__ __attribute__((aligned(16))) u16 Ks3[3][64 * 64];
    __shared__ __attribute__((aligned(16))) u16 Vt3[3][64 * 64];
    __shared__ __attribute__((aligned(16))) u16 Ext[3][64 * 16];
    __shared__ __attribute__((aligned(16))) u16 Pl[4][32 * 68];
    const int tid = threadIdx.x, lane = tid & 63, w = tid >> 6;
    const int c = lane & 15, g = lane >> 4;
    const int Lid = blockIdx.x;
    const int slot = Lid >> 3;
    const int grp = (Lid & 7) * 8 + (slot >> 3);      // (b*16+h)
    const int qi = slot & 7;
    const int b = grp >> 4, h = grp & 15, bh = grp;
    const int s0 = qi * 128;

    const uint4 zz = {0u, 0u, 0u, 0u};
    const bf16x8 zfrag = __builtin_bit_cast(bf16x8, zz);

    bf16x8 aq[2][3];
#pragma unroll
    for (int m = 0; m < 2; ++m) {
        int sl = s0 + w * 32 + m * 16 + c;
        size_t tok = (size_t)b * 1024 + sl;
        aq[m][0] = *(const bf16x8*)(QKV + tok * 3072 + h * 64 + g * 8);
        aq[m][1] = *(const bf16x8*)(QKV + tok * 3072 + h * 64 + 32 + g * 8);
        aq[m][2] = (g < 2) ? *(const bf16x8*)(qcs + ((size_t)h * 1024 + sl) * 16 + g * 8)
                           : zfrag;
    }
    __builtin_amdgcn_sched_barrier(0);

    f32x4 oacc[2][4];
#pragma unroll
    for (int m = 0; m < 2; ++m)
#pragma unroll
        for (int n = 0; n < 4; ++n) {
            f32x4 z = {0.f, 0.f, 0.f, 0.f};
            oacc[m][n] = z;
        }
    float lsum[2] = {0.f, 0.f};

    auto STAGE = [&](int buf, int t0) {
#pragma unroll
        for (int i = 0; i < 2; ++i) {
            int sl2 = i * 256 + tid;
            int row = sl2 >> 3, gi = sl2 & 7;
            int kg = (gi ^ (row & 7)) * 8;
            gload_lds16(QKV + (size_t)(b * 1024 + t0 + row) * 3072 + 1024 + h * 64 + kg,
                        &Ks3[buf][(size_t)(sl2 & ~63) * 8]);
            gload_lds16(Vtg + (size_t)(bh * 64 + row) * 1024 + t0 + kg,
                        &Vt3[buf][(size_t)(sl2 & ~63) * 8]);
        }
        if (tid < 128) {
            int r2 = tid >> 1, g2 = tid & 1;
            gload_lds16(csb + (size_t)(t0 + r2) * 16 + g2 * 8,
                        &Ext[buf][(size_t)(tid & ~63) * 8]);
        }
    };

    STAGE(0, 0);
    STAGE(1, 64);
    __builtin_amdgcn_sched_barrier(0);

    int cur = 0;
    for (int it = 0; it < 16; ++it) {
        if (it < 14) {
            int nb = cur + 2; if (nb >= 3) nb -= 3;
            STAGE(nb, (it + 2) << 6);
            if (w < 2) asm volatile("s_waitcnt vmcnt(10)" ::: "memory");
            else       asm volatile("s_waitcnt vmcnt(8)" ::: "memory");
        } else if (it == 14) {
            if (w < 2) asm volatile("s_waitcnt vmcnt(5)" ::: "memory");
            else       asm volatile("s_waitcnt vmcnt(4)" ::: "memory");
        } else {
            asm volatile("s_waitcnt vmcnt(0)" ::: "memory");
        }
        __builtin_amdgcn_sched_barrier(0);
        __builtin_amdgcn_s_barrier();
        __builtin_amdgcn_sched_barrier(0);

        const u16* ksb = &Ks3[cur][0];
        const u16* vtb = &Vt3[cur][0];
        const u16* exb = &Ext[cur][0];

        f32x4 sacc[2][4];
#pragma unroll
        for (int m = 0; m < 2; ++m)
#pragma unroll
            for (int n = 0; n < 4; ++n) {
                f32x4 z = {0.f, 0.f, 0.f, 0.f};
                sacc[m][n] = z;
            }
        __builtin_amdgcn_s_setprio(1);
#pragma unroll
        for (int ks = 0; ks < 3; ++ks) {
            bf16x8 bk[4];
#pragma unroll
            for (int n = 0; n < 4; ++n) {
                int tr = n * 16 + c;
                if (ks < 2) {
                    int kg = (ks * 4 + g) ^ (tr & 7);
                    bk[n] = *(const bf16x8*)(ksb + tr * 64 + kg * 8);
                } else {
                    bk[n] = (g < 2) ? *(const bf16x8*)(exb + tr * 16 + g * 8) : zfrag;
                }
            }
#pragma unroll
            for (int n = 0; n < 4; ++n)
#pragma unroll
                for (int m = 0; m < 2; ++m)
                    sacc[m][n] = __builtin_amdgcn_mfma_f32_16x16x32_bf16(
                        bk[n], aq[m][ks], sacc[m][n], 0, 0, 0);
        }
        __builtin_amdgcn_s_setprio(0);

#pragma unroll
        for (int m = 0; m < 2; ++m)
#pragma unroll
            for (int n = 0; n < 4; ++n) {
                float p0 = __builtin_amdgcn_exp2f(sacc[m][n][0]);
                float p1 = __builtin_amdgcn_exp2f(sacc[m][n][1]);
                float p2 = __builtin_amdgcn_exp2f(sacc[m][n][2]);
                float p3 = __builtin_amdgcn_exp2f(sacc[m][n][3]);
                lsum[m] += (p0 + p1) + (p2 + p3);
                bf16x4v pk;
                pk[0] = (__bf16)p0; pk[1] = (__bf16)p1;
                pk[2] = (__bf16)p2; pk[3] = (__bf16)p3;
                *(bf16x4v*)(&Pl[w][(m * 16 + c) * 68 + n * 16 + g * 4]) = pk;
            }

        __builtin_amdgcn_s_setprio(1);
#pragma unroll
        for (int ks2 = 0; ks2 < 2; ++ks2) {
            bf16x8 pa[2];
#pragma unroll
            for (int m = 0; m < 2; ++m)
                pa[m] = *(const bf16x8*)(&Pl[w][(m * 16 + c) * 68 + ks2 * 32 + g * 8]);
#pragma unroll
            for (int n = 0; n < 4; ++n) {
                int dr = n * 16 + c;
                int kg = (ks2 * 4 + g) ^ (dr & 7);
                bf16x8 vf = *(const bf16x8*)(vtb + dr * 64 + kg * 8);
#pragma unroll
                for (int m = 0; m < 2; ++m)
                    oacc[m][n] = __builtin_amdgcn_mfma_f32_16x16x32_bf16(
                        pa[m], vf, oacc[m][n], 0, 0, 0);
            }
        }
        __builtin_amdgcn_s_setprio(0);

        __builtin_amdgcn_sched_barrier(0);
        __builtin_amdgcn_s_barrier();
        __builtin_amdgcn_sched_barrier(0);
        cur = (cur == 2) ? 0 : cur + 1;
    }

#pragma unroll
    for (int m = 0; m < 2; ++m) {
        float lt = lsum[m] + __shfl_xor(lsum[m], 16);
        lt += __shfl_xor(lt, 32);
        float inv[4];
#pragma unroll
        for (int q = 0; q < 4; ++q)
            inv[q] = 1.f / __shfl(lt, g * 4 + q);
#pragma unroll
        for (int n = 0; n < 4; ++n)
#pragma unroll
            for (int q = 0; q < 4; ++q) {
                size_t tok = (size_t)b * 1024 + s0 + w * 32 + m * 16 + g * 4 + q;
                Og[tok * 1024 + h * 64 + n * 16 + c] = f2b(oacc[m][n][q] * inv[q]);
            }
    }
}

// ---------------------------------------------------------------------------
// LayerNorm, 2 rows per 512-thr block (bf16 I/O, fp32 math):
// pf <- LN(Yr)*g + b  (residual pre-fused into Yr by Wo EPI=6)
// ---------------------------------------------------------------------------
__global__ __launch_bounds__(512) void ln_k(
    const u16* __restrict__ Yr, u16* __restrict__ Pf,
    const float* __restrict__ g, const float* __restrict__ bt)
{
    const int tid = threadIdx.x;
    const int rw = blockIdx.x * 2 + (tid >> 8);   // row of this half-block
    const int ct = tid & 255;                      // col-thread 0..255
    const u16* yp = Yr + (size_t)rw * M_ + ct * 4;
    u16* pp = Pf + (size_t)rw * M_ + ct * 4;
    ushort4 yv = *(const ushort4*)yp;
    float a[4];
    a[0] = b2f(yv.x); a[1] = b2f(yv.y);
    a[2] = b2f(yv.z); a[3] = b2f(yv.w);
    float s = a[0] + a[1] + a[2] + a[3];
    float q = a[0] * a[0] + a[1] * a[1] + a[2] * a[2] + a[3] * a[3];
#pragma unroll
    for (int o = 1; o < 64; o <<= 1) {
        s += __shfl_xor(s, o);
        q += __shfl_xor(q, o);
    }
    __shared__ float ss[8], qq[8];
    if ((tid & 63) == 0) { ss[tid >> 6] = s; qq[tid >> 6] = q; }
    __syncthreads();
    const int w0 = (tid >> 8) * 4;                 // this row's wave group
    s = ss[w0 + 0] + ss[w0 + 1] + ss[w0 + 2] + ss[w0 + 3];
    q = qq[w0 + 0] + qq[w0 + 1] + qq[w0 + 2] + qq[w0 + 3];
    float mu = s * (1.0f / 1024.0f);
    float var = q * (1.0f / 1024.0f) - mu * mu;
    float inv = rsqrtf(var + 1e-5f);
    float4 gv = *(const float4*)(g + (ct << 2));
    float4 bv = *(const float4*)(bt + (ct << 2));
    *(ushort4*)pp = make_ushort4(
        f2b((a[0] - mu) * inv * gv.x + bv.x),
        f2b((a[1] - mu) * inv * gv.y + bv.y),
        f2b((a[2] - mu) * inv * gv.z + bv.z),
        f2b((a[3] - mu) * inv * gv.w + bv.w));
}

// ---------------------------------------------------------------------------
extern "C" void kernel_launch(void* const* d_in, const int* in_sizes, int n_in,
                              void* d_out, int out_size, void* d_ws, size_t ws_size,
                              hipStream_t stream)
{
    const float* x     = (const float*)d_in[0];
    const float* Wemb  = (const float*)d_in[1];
    const float* bemb  = (const float*)d_in[2];
    // d_in[3]=Wamp, d_in[4]=bamp dead (mean of softmax = 1/F)
    const float* freqs = (const float*)d_in[5];
    const float* poff  = (const float*)d_in[6];
    const float* Wq    = (const float*)d_in[7];
    const float* bq    = (const float*)d_in[8];
    const float* Wk    = (const float*)d_in[9];
    const float* bk    = (const float*)d_in[10];
    const float* Wv    = (const float*)d_in[11];
    const float* bv    = (const float*)d_in[12];
    const float* Wo    = (const float*)d_in[13];
    const float* bo    = (const float*)d_in[14];
    const float* pbias = (const float*)d_in[15];
    const float* lng   = (const float*)d_in[16];
    const float* lnb   = (const float*)d_in[17];
    const float* W1    = (const float*)d_in[18];
    const float* b1    = (const float*)d_in[19];
    const float* W2    = (const float*)d_in[20];
    const float* b2    = (const float*)d_in[21];
    float* out = (float*)d_out;

    char* ws = (char*)d_ws;
    const size_t MB = 1 << 20;
    u16* pf    = (u16*)(ws);                            // 4096x1024   8MB
    u16* QKV   = (u16*)(ws + 8 * MB);                   // 4096x3072  24MB (also Yr)
    u16* Ab    = (u16*)(ws + 32 * MB);                  // 4096x1024   8MB (also hdn)
    u16* Vtg   = (u16*)(ws + 40 * MB);                  // [bh*64+d][1024] 8MB
    u16* WqkvT = (u16*)(ws + 48 * MB);                  // 2x 3072x1024 12MB
    u16* WoT   = (u16*)(ws + 60 * MB);                  // 2x 1024x1024  4MB
    u16* WembT = (u16*)(ws + 64 * MB);                  // 1024x256   0.5MB
    u16* W1T   = (u16*)(ws + 64 * MB + 512 * 1024);     // 512x1024     1MB
    u16* W2T   = (u16*)(ws + 65 * MB + 512 * 1024);     // 256x512   0.25MB
    u16* xb    = (u16*)(ws + 66 * MB);                  // 4096x256     2MB
    u16* qcs   = (u16*)(ws + 68 * MB);                  // 2x16x1024x16 1MB
    u16* csb   = (u16*)(ws + 69 * MB);                  // 1024x16    32KB
    float* bqkv = (float*)(ws + 69 * MB + 64 * 1024);   // 2x3072 f32 24KB

    dim3 blk(256);
    prep_k<<<10168, blk, 0, stream>>>(x, Wemb, Wq, Wk, Wv, Wo, W1, W2,
                                      freqs, poff, pbias, bq, bk, bv,
                                      xb, WembT, WqkvT, WoT, W1T, W2T,
                                      qcs, csb, bqkv);

    // pf = |x @ Wemb + bemb| * 0.125   (BM=32: 1024 blocks, 4/CU)
    mgemm_k<1, 1, 32><<<dim3(1024), blk, 0, stream>>>(
        xb, WembT, bemb, pf, nullptr, 1024, 256, 8);

    for (int l = 0; l < L_; ++l) {
        // fused QKV projection (Q pre-scaled; V written directly transposed)
        mgemm_k<5, 1, 128><<<dim3(768), blk, 0, stream>>>(
            pf, WqkvT + (size_t)l * 3072 * 1024, bqkv + l * 3072, QKV, Vtg,
            3072, 1024, 24);
        fattn_k<<<dim3(512), blk, 0, stream>>>(
            QKV, Vtg, csb, qcs + (size_t)l * H_ * S_ * 16, Ab);
        // Wo projection + residual add fused (BM=64, 512 blocks)
        mgemm_k<6, 1, 64><<<dim3(512), blk, 0, stream>>>(
            Ab, WoT + (size_t)l * M_ * M_, bo + l * M_, QKV /*Yr*/, pf,
            1024, 1024, 8);
        ln_k<<<dim3(NT_ / 2), dim3(512), 0, stream>>>(QKV, pf, lng + l * M_, lnb + l * M_);
    }

    // hdn = relu(pf @ W1 + b1) -> Ab ; out = hdn @ W2 + b2 (fp32)
    mgemm_k<2, 1, 32><<<dim3(512), blk, 0, stream>>>(
        pf, W1T, b1, Ab, nullptr, 512, 1024, 4);
    mgemm_k<0, 0, 32><<<dim3(256), blk, 0, stream>>>(
        Ab, W2T, b2, out, nullptr, 256, 512, 2);
}